// Round 9
// baseline (224.625 us; speedup 1.0000x reference)
//
#include <hip/hip_runtime.h>
#include <math.h>

typedef unsigned int  uint;
typedef unsigned short ushort;

// Problem constants
constexpr int NPTS = 30000;
constexpr int NPAD = 30080;  // 235 * 128, padded row count for tail-safe frag loads
constexpr int CIN  = 128;
constexpr int OC   = 128;   // O
constexpr int NH   = 8;     // heads
constexpr int NS   = 16;    // neighbors
constexpr int DH   = 16;    // O/H
constexpr int OSH  = 16;    // O/SHARE
constexpr float EPSF = 1e-5f;

typedef __attribute__((ext_vector_type(8))) short  bf16x8;
typedef __attribute__((ext_vector_type(8))) __fp16 f16x8;
typedef __attribute__((ext_vector_type(4))) float  f32x4;
typedef __attribute__((ext_vector_type(2))) __fp16 h16x2;

__device__ __forceinline__ ushort f2bf(float f) {
    uint u = __float_as_uint(f);
    u += 0x7fff + ((u >> 16) & 1);   // RNE
    return (ushort)(u >> 16);
}
__device__ __forceinline__ void bf2f2(uint u, float& f0, float& f1) {
    f0 = __uint_as_float(u << 16);
    f1 = __uint_as_float(u & 0xffff0000u);
}

// ---------------------------------------------------------------------------
// Kernel 0: prep. Blocks [0, 3760): x fp32 -> bf16 (rows >= NPTS zero-filled).
// Blocks 3760..3762: W{q,k,v} -> bf16 transposed WT[o][k] = W[k][o].
// Block 3763: Ww1^T as f16 (A-fragment source) + rowmean(Ww2)/mean(bw2).
// ---------------------------------------------------------------------------
constexpr int XB_BLOCKS = (NPAD * CIN / 4) / 256;   // 3760

__global__ __launch_bounds__(256) void prep_kernel(
    const float* __restrict__ x,
    const float* __restrict__ Wq, const float* __restrict__ Wk, const float* __restrict__ Wv,
    const float* __restrict__ Ww1, const float* __restrict__ Ww2, const float* __restrict__ bw2,
    ushort* __restrict__ xb, ushort* __restrict__ WT,
    ushort* __restrict__ Ww1T, float* __restrict__ rmean)
{
    const int b = blockIdx.x;
    const int t = threadIdx.x;
    if (b < XB_BLOCKS) {
        int e   = (b * 256 + t) * 4;       // element index
        int row = e >> 7;
        uint2 o = make_uint2(0, 0);
        if (row < NPTS) {
            float4 f = *(const float4*)(x + e);
            o.x = (uint)f2bf(f.x) | ((uint)f2bf(f.y) << 16);
            o.y = (uint)f2bf(f.z) | ((uint)f2bf(f.w) << 16);
        }
        *(uint2*)(xb + e) = o;
    } else if (b < XB_BLOCKS + 3) {
        int mat = b - XB_BLOCKS;
        const float* W = (mat == 0) ? Wq : (mat == 1 ? Wk : Wv);
        ushort* T = WT + mat * OC * CIN;
        if (t < OC) {
            for (int k = 0; k < CIN; ++k)
                T[t * CIN + k] = f2bf(W[k * OC + t]);
        }
    } else {
        // Ww1T[o2*16 + d] = (f16) Ww1[d*16 + o2]
        if (t < 256) {
            int o2 = t >> 4, d = t & 15;
            __fp16 h = (__fp16)Ww1[d * OSH + o2];
            Ww1T[o2 * 16 + d] = *(ushort*)&h;
        }
        if (t < 16) {
            float acc = 0.f;
            #pragma unroll
            for (int o2 = 0; o2 < OSH; ++o2) acc += Ww2[t * OSH + o2];
            rmean[t] = acc * (1.f / OSH);
        } else if (t == 16) {
            float acc = 0.f;
            #pragma unroll
            for (int o2 = 0; o2 < OSH; ++o2) acc += bw2[o2];
            rmean[OSH] = acc * (1.f / OSH);
        }
    }
}

// ---------------------------------------------------------------------------
// Kernel 1: QKV projection via bf16 MFMA (16x16x32), staging-free.
// ---------------------------------------------------------------------------
__global__ __launch_bounds__(256) void qkv_mfma(
    const ushort* __restrict__ xb, const ushort* __restrict__ WT,
    const float* __restrict__ bq, const float* __restrict__ bk, const float* __restrict__ bv,
    ushort* __restrict__ yq, ushort* __restrict__ yk, ushort* __restrict__ yv)
{
    const int mat = blockIdx.y;
    const float* bias = (mat == 0) ? bq : (mat == 1 ? bk : bv);
    ushort* y         = (mat == 0) ? yq : (mat == 1 ? yk : yv);
    const ushort* T   = WT + mat * OC * CIN;

    const int n0   = blockIdx.x * 128;
    const int t    = threadIdx.x;
    const int wave = t >> 6;
    const int lane = t & 63;
    const int m16  = lane & 15;
    const int quad = lane >> 4;

    f32x4 acc[2][8];
    #pragma unroll
    for (int mt = 0; mt < 2; ++mt)
        #pragma unroll
        for (int nt = 0; nt < 8; ++nt)
            acc[mt][nt] = (f32x4){0.f, 0.f, 0.f, 0.f};

    const ushort* arow0 = xb + (size_t)(n0 + wave * 32 + m16) * CIN;
    const ushort* arow1 = arow0 + 16 * CIN;

    #pragma unroll
    for (int ks = 0; ks < 4; ++ks) {
        const int kb = ks * 32 + quad * 8;
        bf16x8 a0 = *(const bf16x8*)(arow0 + kb);
        bf16x8 a1 = *(const bf16x8*)(arow1 + kb);
        #pragma unroll
        for (int nt = 0; nt < 8; ++nt) {
            bf16x8 bfr = *(const bf16x8*)(T + (size_t)(nt * 16 + m16) * CIN + kb);
            acc[0][nt] = __builtin_amdgcn_mfma_f32_16x16x32_bf16(a0, bfr, acc[0][nt], 0, 0, 0);
            acc[1][nt] = __builtin_amdgcn_mfma_f32_16x16x32_bf16(a1, bfr, acc[1][nt], 0, 0, 0);
        }
    }

    #pragma unroll
    for (int mt = 0; mt < 2; ++mt) {
        #pragma unroll
        for (int nt = 0; nt < 8; ++nt) {
            const int col = nt * 16 + m16;
            const float bcol = bias[col];
            #pragma unroll
            for (int r = 0; r < 4; ++r) {
                int row = n0 + wave * 32 + mt * 16 + quad * 4 + r;
                if (row < NPTS)
                    y[(size_t)row * OC + col] = f2bf(acc[mt][nt][r] + bcol);
            }
        }
    }
}

// ---------------------------------------------------------------------------
// Kernel 2: per-point attention. 1 point per block, 128 threads = (s,h).
// The a@Ww1 matvec is done on the matrix pipe: per wave, 4x
// mfma_f32_16x16x32_f16 with items as B-columns (D[o2][item]); K=16 real,
// quads 2/3 supply zero fragments. All a/w1 LDS traffic is wave-local
// (no extra barriers). w1Buf unions with s_contrib (time-disjoint across
// the two softmax barriers).
// ---------------------------------------------------------------------------
constexpr int ASTRIDE = 24;   // ushort stride for aBuf rows (48 B)
constexpr int WSTRIDE = 20;   // float stride for w1Buf rows (80 B)

__global__ __launch_bounds__(128) void attn_kernel(
    const float* __restrict__ p, const int* __restrict__ idx,
    const ushort* __restrict__ xq, const ushort* __restrict__ xk, const ushort* __restrict__ xv,
    const float* __restrict__ Wp1, const float* __restrict__ bp1,
    const float* __restrict__ gp,  const float* __restrict__ betap,
    const float* __restrict__ Wp2, const float* __restrict__ bp2,
    const float* __restrict__ gw1, const float* __restrict__ betaw1,
    const ushort* __restrict__ Ww1T, const float* __restrict__ bw1,
    const float* __restrict__ gw2, const float* __restrict__ betaw2,
    const float* __restrict__ rmean,
    float* __restrict__ out)
{
    const int n = blockIdx.x;
    const int t = threadIdx.x;   // 0..127
    const int s = t >> 3;        // neighbor
    const int h = t & 7;         // head

    __shared__ float  s_t[NS][4];
    __shared__ float  s_logit[NS][NH];
    __shared__ float  s_mx[NH];
    __shared__ float  s_inv[NH];
    __shared__ ushort aBuf[128 * ASTRIDE];            // 6 KB, f16 a-vectors
    __shared__ float  s_big[128 * WSTRIDE];           // 10 KB: w1Buf, then s_contrib

    if (t < NS) {
        int ss = t;
        int j = idx[n * NS + ss];
        float pr0 = p[j * 3 + 0] - p[n * 3 + 0];
        float pr1 = p[j * 3 + 1] - p[n * 3 + 1];
        float pr2 = p[j * 3 + 2] - p[n * 3 + 2];
        float u[3];
        #pragma unroll
        for (int c = 0; c < 3; ++c)
            u[c] = bp1[c] + pr0 * Wp1[0 * 3 + c] + pr1 * Wp1[1 * 3 + c] + pr2 * Wp1[2 * 3 + c];
        float m   = (u[0] + u[1] + u[2]) * (1.f / 3.f);
        float d0 = u[0] - m, d1 = u[1] - m, d2 = u[2] - m;
        float var = (d0 * d0 + d1 * d1 + d2 * d2) * (1.f / 3.f);
        float inv = rsqrtf(var + EPSF);
        #pragma unroll
        for (int c = 0; c < 3; ++c)
            s_t[ss][c] = fmaxf((u[c] - m) * inv * gp[c] + betap[c], 0.f);
    }
    __syncthreads();

    const int j = idx[n * NS + s];
    const float t0 = s_t[s][0], t1 = s_t[s][1], t2 = s_t[s][2];
    const int obase = h * DH;

    // pe for this head slice — explicit float4 weight loads
    float pe[DH];
    {
        const float* W0 = Wp2 + obase;
        const float* W1 = Wp2 + OC + obase;
        const float* W2 = Wp2 + 2 * OC + obase;
        const float* B  = bp2 + obase;
        #pragma unroll
        for (int q = 0; q < 4; ++q) {
            float4 a0 = *(const float4*)(W0 + q * 4);
            float4 a1 = *(const float4*)(W1 + q * 4);
            float4 a2 = *(const float4*)(W2 + q * 4);
            float4 bb = *(const float4*)(B + q * 4);
            pe[q * 4 + 0] = bb.x + t0 * a0.x + t1 * a1.x + t2 * a2.x;
            pe[q * 4 + 1] = bb.y + t0 * a0.y + t1 * a1.y + t2 * a2.y;
            pe[q * 4 + 2] = bb.z + t0 * a0.z + t1 * a1.z + t2 * a2.z;
            pe[q * 4 + 3] = bb.w + t0 * a0.w + t1 * a1.w + t2 * a2.w;
        }
    }

    // gather q,k,v (bf16) and build r = kg + pe - xq
    float vv[DH], r[DH];
    {
        const uint4* k4 = (const uint4*)(xk + (size_t)j * OC + obase);
        const uint4* v4 = (const uint4*)(xv + (size_t)j * OC + obase);
        const uint4* q4 = (const uint4*)(xq + (size_t)n * OC + obase);
        uint4 ku0 = k4[0], ku1 = k4[1];
        uint4 vu0 = v4[0], vu1 = v4[1];
        uint4 qu0 = q4[0], qu1 = q4[1];
        float kf[DH], qf[DH];
        bf2f2(ku0.x, kf[0], kf[1]);   bf2f2(ku0.y, kf[2], kf[3]);
        bf2f2(ku0.z, kf[4], kf[5]);   bf2f2(ku0.w, kf[6], kf[7]);
        bf2f2(ku1.x, kf[8], kf[9]);   bf2f2(ku1.y, kf[10], kf[11]);
        bf2f2(ku1.z, kf[12], kf[13]); bf2f2(ku1.w, kf[14], kf[15]);
        bf2f2(vu0.x, vv[0], vv[1]);   bf2f2(vu0.y, vv[2], vv[3]);
        bf2f2(vu0.z, vv[4], vv[5]);   bf2f2(vu0.w, vv[6], vv[7]);
        bf2f2(vu1.x, vv[8], vv[9]);   bf2f2(vu1.y, vv[10], vv[11]);
        bf2f2(vu1.z, vv[12], vv[13]); bf2f2(vu1.w, vv[14], vv[15]);
        bf2f2(qu0.x, qf[0], qf[1]);   bf2f2(qu0.y, qf[2], qf[3]);
        bf2f2(qu0.z, qf[4], qf[5]);   bf2f2(qu0.w, qf[6], qf[7]);
        bf2f2(qu1.x, qf[8], qf[9]);   bf2f2(qu1.y, qf[10], qf[11]);
        bf2f2(qu1.z, qf[12], qf[13]); bf2f2(qu1.w, qf[14], qf[15]);
        #pragma unroll
        for (int d = 0; d < DH; ++d)
            r[d] = kf[d] + pe[d] - qf[d];
    }

    // LN over D=16 + relu
    float a[DH];
    {
        float m = 0.f;
        #pragma unroll
        for (int d = 0; d < DH; ++d) m += r[d];
        m *= (1.f / DH);
        float var = 0.f;
        #pragma unroll
        for (int d = 0; d < DH; ++d) { float dd = r[d] - m; var += dd * dd; }
        var *= (1.f / DH);
        float inv = rsqrtf(var + EPSF);
        #pragma unroll
        for (int d = 0; d < DH; ++d)
            a[d] = fmaxf((r[d] - m) * inv * gw1[d] + betaw1[d], 0.f);
    }

    // ---- w1 = a @ Ww1 via MFMA (items as B-columns) ----
    // pack a -> f16, write 32B to aBuf (wave-local)
    {
        uint4 u0, u1;
        h16x2 pk;
        pk = __builtin_amdgcn_cvt_pkrtz(a[0],  a[1]);  u0.x = *(uint*)&pk;
        pk = __builtin_amdgcn_cvt_pkrtz(a[2],  a[3]);  u0.y = *(uint*)&pk;
        pk = __builtin_amdgcn_cvt_pkrtz(a[4],  a[5]);  u0.z = *(uint*)&pk;
        pk = __builtin_amdgcn_cvt_pkrtz(a[6],  a[7]);  u0.w = *(uint*)&pk;
        pk = __builtin_amdgcn_cvt_pkrtz(a[8],  a[9]);  u1.x = *(uint*)&pk;
        pk = __builtin_amdgcn_cvt_pkrtz(a[10], a[11]); u1.y = *(uint*)&pk;
        pk = __builtin_amdgcn_cvt_pkrtz(a[12], a[13]); u1.z = *(uint*)&pk;
        pk = __builtin_amdgcn_cvt_pkrtz(a[14], a[15]); u1.w = *(uint*)&pk;
        *(uint4*)&aBuf[t * ASTRIDE]     = u0;
        *(uint4*)&aBuf[t * ASTRIDE + 8] = u1;
    }

    const int wave = t >> 6;
    const int lane = t & 63;
    const int m16  = lane & 15;
    const int quad = lane >> 4;

    uint4 zu = make_uint4(0, 0, 0, 0);
    f16x8 zf = *(f16x8*)&zu;

    // A-fragment: Ww1T[m16][quad*8 .. +7] for quad<2, zero otherwise
    f16x8 afrag = zf;
    if (quad < 2) afrag = *(const f16x8*)(Ww1T + m16 * 16 + quad * 8);

    float* w1Buf = s_big;
    #pragma unroll
    for (int g = 0; g < 4; ++g) {
        const int item = wave * 64 + g * 16 + m16;
        f16x8 bfrag = zf;
        if (quad < 2) bfrag = *(const f16x8*)&aBuf[item * ASTRIDE + quad * 8];
        f32x4 accg = __builtin_amdgcn_mfma_f32_16x16x32_f16(afrag, bfrag,
                                                            (f32x4){0.f, 0.f, 0.f, 0.f}, 0, 0, 0);
        *(f32x4*)&w1Buf[item * WSTRIDE + quad * 4] = accg;
    }

    // read back own item's w1, add bias
    float w1[OSH];
    {
        f32x4 r0 = *(f32x4*)&w1Buf[t * WSTRIDE + 0];
        f32x4 r1 = *(f32x4*)&w1Buf[t * WSTRIDE + 4];
        f32x4 r2 = *(f32x4*)&w1Buf[t * WSTRIDE + 8];
        f32x4 r3 = *(f32x4*)&w1Buf[t * WSTRIDE + 12];
        #pragma unroll
        for (int q = 0; q < 4; ++q) {
            w1[0 + q]  = r0[q] + bw1[0 + q];
            w1[4 + q]  = r1[q] + bw1[4 + q];
            w1[8 + q]  = r2[q] + bw1[8 + q];
            w1[12 + q] = r3[q] + bw1[12 + q];
        }
    }

    // LN over OS=16 + relu, fused (@Ww2 + bw2).mean(-1) via rowmean
    float logit;
    {
        float m = 0.f;
        #pragma unroll
        for (int o2 = 0; o2 < OSH; ++o2) m += w1[o2];
        m *= (1.f / OSH);
        float var = 0.f;
        #pragma unroll
        for (int o2 = 0; o2 < OSH; ++o2) { float dd = w1[o2] - m; var += dd * dd; }
        var *= (1.f / OSH);
        float inv = rsqrtf(var + EPSF);
        logit = rmean[OSH];
        #pragma unroll
        for (int o2 = 0; o2 < OSH; ++o2) {
            float bv2 = fmaxf((w1[o2] - m) * inv * gw2[o2] + betaw2[o2], 0.f);
            logit = fmaf(bv2, rmean[o2], logit);
        }
    }

    s_logit[s][h] = logit;
    __syncthreads();

    if (t < NH) {
        float mx = -1e30f;
        #pragma unroll
        for (int ss = 0; ss < NS; ++ss) mx = fmaxf(mx, s_logit[ss][t]);
        float denom = 0.f;
        #pragma unroll
        for (int ss = 0; ss < NS; ++ss) denom += __expf(s_logit[ss][t] - mx);
        s_mx[t] = mx;
        s_inv[t] = 1.f / denom;
    }
    __syncthreads();   // also fences all w1Buf reads before s_contrib reuse

    float w = __expf(logit - s_mx[h]) * s_inv[h];

    float (*s_contrib)[OC + 4] = (float (*)[OC + 4])s_big;   // 16 x 132 <= 128*20
    #pragma unroll
    for (int d = 0; d < DH; ++d)
        s_contrib[s][obase + d] = (vv[d] + pe[d]) * w;
    __syncthreads();

    float acc = 0.f;
    #pragma unroll
    for (int ss = 0; ss < NS; ++ss) acc += s_contrib[ss][t];
    out[(size_t)n * OC + t] = acc;
}

// ---------------------------------------------------------------------------
extern "C" void kernel_launch(void* const* d_in, const int* in_sizes, int n_in,
                              void* d_out, int out_size, void* d_ws, size_t ws_size,
                              hipStream_t stream) {
    const float* p     = (const float*)d_in[0];
    const float* x     = (const float*)d_in[1];
    const int*   idx   = (const int*)d_in[2];
    const float* Wq    = (const float*)d_in[3];
    const float* bq    = (const float*)d_in[4];
    const float* Wk    = (const float*)d_in[5];
    const float* bk    = (const float*)d_in[6];
    const float* Wv    = (const float*)d_in[7];
    const float* bv    = (const float*)d_in[8];
    const float* Wp1   = (const float*)d_in[9];
    const float* bp1   = (const float*)d_in[10];
    const float* gp    = (const float*)d_in[11];
    const float* betap = (const float*)d_in[12];
    const float* Wp2   = (const float*)d_in[13];
    const float* bp2   = (const float*)d_in[14];
    const float* gw1   = (const float*)d_in[15];
    const float* betaw1= (const float*)d_in[16];
    const float* Ww1   = (const float*)d_in[17];
    const float* bw1   = (const float*)d_in[18];
    const float* gw2   = (const float*)d_in[19];
    const float* betaw2= (const float*)d_in[20];
    const float* Ww2   = (const float*)d_in[21];
    const float* bw2   = (const float*)d_in[22];
    float* out = (float*)d_out;

    // workspace layout (all 16B-aligned):
    ushort* xb = (ushort*)d_ws;                        // NPAD*128 bf16
    ushort* WT = xb + (size_t)NPAD * CIN;              // 3*128*128 bf16
    ushort* xq = WT + 3 * OC * CIN;                    // N*128 bf16
    ushort* xk = xq + (size_t)NPTS * OC;
    ushort* xv = xk + (size_t)NPTS * OC;
    ushort* Ww1T  = xv + (size_t)NPTS * OC;            // 256 f16
    float*  rmean = (float*)(Ww1T + 256);              // 17 floats

    prep_kernel<<<XB_BLOCKS + 4, 256, 0, stream>>>(x, Wq, Wk, Wv, Ww1, Ww2, bw2,
                                                   xb, WT, Ww1T, rmean);

    dim3 g1(NPAD / 128, 3);   // 235 x 3
    qkv_mfma<<<g1, 256, 0, stream>>>(xb, WT, bq, bk, bv, xq, xk, xv);

    attn_kernel<<<NPTS, 128, 0, stream>>>(p, idx, xq, xk, xv,
                                          Wp1, bp1, gp, betap, Wp2, bp2,
                                          gw1, betaw1, Ww1T, bw1,
                                          gw2, betaw2, rmean, out);
}

// Round 10
// 196.222 us; speedup vs baseline: 1.1448x; 1.1448x over previous
//
#include <hip/hip_runtime.h>
#include <math.h>

typedef unsigned int  uint;
typedef unsigned short ushort;

// Problem constants
constexpr int NPTS = 30000;
constexpr int NPAD = 30080;  // 235 * 128
constexpr int CIN  = 128;
constexpr int OC   = 128;   // O
constexpr int NH   = 8;     // heads
constexpr int NS   = 16;    // neighbors
constexpr int DH   = 16;    // O/H
constexpr int OSH  = 16;    // O/SHARE
constexpr float EPSF = 1e-5f;

typedef __attribute__((ext_vector_type(8))) short  bf16x8;
typedef __attribute__((ext_vector_type(4))) float  f32x4;
typedef __attribute__((ext_vector_type(2))) __fp16 h2;

__device__ __forceinline__ ushort f2bf(float f) {
    uint u = __float_as_uint(f);
    u += 0x7fff + ((u >> 16) & 1);   // RNE
    return (ushort)(u >> 16);
}
__device__ __forceinline__ ushort f2h(float f) {
    __fp16 h = (__fp16)f;
    return *(ushort*)&h;
}
__device__ __forceinline__ uint pk2(float a, float b) {
    h2 v = __builtin_amdgcn_cvt_pkrtz(a, b);
    return *(uint*)&v;
}
__device__ __forceinline__ h2 asH2(uint u) { return *(h2*)&u; }

#if defined(__has_builtin)
#if __has_builtin(__builtin_elementwise_max)
#define PKMAX(a, b) __builtin_elementwise_max(a, b)
#endif
#endif
#ifndef PKMAX
__device__ __forceinline__ h2 PKMAX(h2 a, h2 b) {
    h2 r; r[0] = a[0] > b[0] ? a[0] : b[0]; r[1] = a[1] > b[1] ? a[1] : b[1]; return r;
}
#endif

// PACKS layout (uints):
//   [0,128)   Ww1p    : pairs (Ww1[2dp][o], Ww1[2dp+1][o]) at [dp*16+o]
//   [128,320) Wp2p    : c=0..2, pairs over o: [128 + c*64 + j] = (Wp2[c][2j], Wp2[c][2j+1])
//   [320,384) bp2p    : pairs of bp2
//   [384,392) gw1p  [392,400) betaw1p  [400,408) gw2p  [408,416) betaw2p
//   [416,424) rmeanp  : pairs of rowmean(Ww2)/16
//   floats (same buffer viewed as float*):
//   [424,440) bw1 (f32)   [440] mean(bw2)
constexpr int PK_WW1   = 0;
constexpr int PK_WP2   = 128;
constexpr int PK_BP2   = 320;
constexpr int PK_GW1   = 384;
constexpr int PK_BW1P  = 392;   // betaw1 pairs
constexpr int PK_GW2   = 400;
constexpr int PK_BW2P  = 408;   // betaw2 pairs
constexpr int PK_RM    = 416;
constexpr int PKF_BW1  = 424;   // float view
constexpr int PKF_RMB  = 440;   // float view

// ---------------------------------------------------------------------------
// Kernel 0: prep.
// ---------------------------------------------------------------------------
constexpr int XB_BLOCKS = (NPAD * CIN / 4) / 256;   // 3760

__global__ __launch_bounds__(256) void prep_kernel(
    const float* __restrict__ x,
    const float* __restrict__ Wq, const float* __restrict__ Wk, const float* __restrict__ Wv,
    const float* __restrict__ Wp2, const float* __restrict__ bp2,
    const float* __restrict__ gw1, const float* __restrict__ betaw1,
    const float* __restrict__ Ww1, const float* __restrict__ bw1,
    const float* __restrict__ gw2, const float* __restrict__ betaw2,
    const float* __restrict__ Ww2, const float* __restrict__ bw2,
    ushort* __restrict__ xb, ushort* __restrict__ WT, uint* __restrict__ PK)
{
    const int b = blockIdx.x;
    const int t = threadIdx.x;
    if (b < XB_BLOCKS) {
        int e   = (b * 256 + t) * 4;
        int row = e >> 7;
        uint2 o = make_uint2(0, 0);
        if (row < NPTS) {
            float4 f = *(const float4*)(x + e);
            o.x = (uint)f2bf(f.x) | ((uint)f2bf(f.y) << 16);
            o.y = (uint)f2bf(f.z) | ((uint)f2bf(f.w) << 16);
        }
        *(uint2*)(xb + e) = o;
    } else if (b < XB_BLOCKS + 3) {
        int mat = b - XB_BLOCKS;
        const float* W = (mat == 0) ? Wq : (mat == 1 ? Wk : Wv);
        ushort* T = WT + mat * OC * CIN;
        if (t < OC) {
            for (int k = 0; k < CIN; ++k)
                T[t * CIN + k] = f2bf(W[k * OC + t]);
        }
    } else {
        float* FPK = (float*)PK;
        if (t < 128) {
            int dp = t >> 4, o = t & 15;
            PK[PK_WW1 + t] = pk2(Ww1[(2 * dp) * OSH + o], Ww1[(2 * dp + 1) * OSH + o]);
        }
        if (t < 192) {
            int c = t >> 6, jj = t & 63;
            PK[PK_WP2 + t] = pk2(Wp2[c * OC + 2 * jj], Wp2[c * OC + 2 * jj + 1]);
        }
        if (t < 64)
            PK[PK_BP2 + t] = pk2(bp2[2 * t], bp2[2 * t + 1]);
        if (t < 8) {
            PK[PK_GW1 + t]  = pk2(gw1[2 * t],    gw1[2 * t + 1]);
            PK[PK_BW1P + t] = pk2(betaw1[2 * t], betaw1[2 * t + 1]);
            PK[PK_GW2 + t]  = pk2(gw2[2 * t],    gw2[2 * t + 1]);
            PK[PK_BW2P + t] = pk2(betaw2[2 * t], betaw2[2 * t + 1]);
            float r0 = 0.f, r1 = 0.f;
            #pragma unroll
            for (int o2 = 0; o2 < OSH; ++o2) {
                r0 += Ww2[(2 * t) * OSH + o2];
                r1 += Ww2[(2 * t + 1) * OSH + o2];
            }
            PK[PK_RM + t] = pk2(r0 * (1.f / OSH), r1 * (1.f / OSH));
        }
        if (t < 16)
            FPK[PKF_BW1 + t] = bw1[t];
        if (t == 16) {
            float acc = 0.f;
            #pragma unroll
            for (int o2 = 0; o2 < OSH; ++o2) acc += bw2[o2];
            FPK[PKF_RMB] = acc * (1.f / OSH);
        }
    }
}

// ---------------------------------------------------------------------------
// Kernel 1: QKV projection via bf16 MFMA (16x16x32), staging-free.
// Outputs f16 (better precision than bf16, enables packed attn math).
// ---------------------------------------------------------------------------
__global__ __launch_bounds__(256) void qkv_mfma(
    const ushort* __restrict__ xb, const ushort* __restrict__ WT,
    const float* __restrict__ bq, const float* __restrict__ bk, const float* __restrict__ bv,
    ushort* __restrict__ yq, ushort* __restrict__ yk, ushort* __restrict__ yv)
{
    const int mat = blockIdx.y;
    const float* bias = (mat == 0) ? bq : (mat == 1 ? bk : bv);
    ushort* y         = (mat == 0) ? yq : (mat == 1 ? yk : yv);
    const ushort* T   = WT + mat * OC * CIN;

    const int n0   = blockIdx.x * 128;
    const int t    = threadIdx.x;
    const int wave = t >> 6;
    const int lane = t & 63;
    const int m16  = lane & 15;
    const int quad = lane >> 4;

    f32x4 acc[2][8];
    #pragma unroll
    for (int mt = 0; mt < 2; ++mt)
        #pragma unroll
        for (int nt = 0; nt < 8; ++nt)
            acc[mt][nt] = (f32x4){0.f, 0.f, 0.f, 0.f};

    const ushort* arow0 = xb + (size_t)(n0 + wave * 32 + m16) * CIN;
    const ushort* arow1 = arow0 + 16 * CIN;

    #pragma unroll
    for (int ks = 0; ks < 4; ++ks) {
        const int kb = ks * 32 + quad * 8;
        bf16x8 a0 = *(const bf16x8*)(arow0 + kb);
        bf16x8 a1 = *(const bf16x8*)(arow1 + kb);
        #pragma unroll
        for (int nt = 0; nt < 8; ++nt) {
            bf16x8 bfr = *(const bf16x8*)(T + (size_t)(nt * 16 + m16) * CIN + kb);
            acc[0][nt] = __builtin_amdgcn_mfma_f32_16x16x32_bf16(a0, bfr, acc[0][nt], 0, 0, 0);
            acc[1][nt] = __builtin_amdgcn_mfma_f32_16x16x32_bf16(a1, bfr, acc[1][nt], 0, 0, 0);
        }
    }

    #pragma unroll
    for (int mt = 0; mt < 2; ++mt) {
        #pragma unroll
        for (int nt = 0; nt < 8; ++nt) {
            const int col = nt * 16 + m16;
            const float bcol = bias[col];
            #pragma unroll
            for (int r = 0; r < 4; ++r) {
                int row = n0 + wave * 32 + mt * 16 + quad * 4 + r;
                if (row < NPTS)
                    y[(size_t)row * OC + col] = f2h(acc[mt][nt][r] + bcol);
            }
        }
    }
}

// ---------------------------------------------------------------------------
// Kernel 2: per-point attention. 1 point/block, 128 threads = (s,h).
// Entire 16-wide elementwise pipeline in packed f16 (v_pk_*):
// q/k/v stored f16 (zero-conversion gather), pe/r/LN1 packed, fdot2 matvec
// consumes packed a directly, LN2+logit packed, contrib packed (halves LDS).
// ---------------------------------------------------------------------------
__global__ __launch_bounds__(128) void attn_kernel(
    const float* __restrict__ p, const int* __restrict__ idx,
    const ushort* __restrict__ xq, const ushort* __restrict__ xk, const ushort* __restrict__ xv,
    const float* __restrict__ Wp1, const float* __restrict__ bp1,
    const float* __restrict__ gp,  const float* __restrict__ betap,
    const uint* __restrict__ PK,
    float* __restrict__ out)
{
    const int n = blockIdx.x;
    const int t = threadIdx.x;   // 0..127
    const int s = t >> 3;        // neighbor
    const int h = t & 7;         // head

    const float* FPK = (const float*)PK;

    __shared__ float s_t[NS][4];
    __shared__ float s_logit[NS][NH];
    __shared__ float s_mx[NH];
    __shared__ float s_inv[NH];
    __shared__ uint  s_c[NS][68];   // packed f16 contrib pairs, 4352 B

    if (t < NS) {
        int ss = t;
        int j = idx[n * NS + ss];
        float pr0 = p[j * 3 + 0] - p[n * 3 + 0];
        float pr1 = p[j * 3 + 1] - p[n * 3 + 1];
        float pr2 = p[j * 3 + 2] - p[n * 3 + 2];
        float u[3];
        #pragma unroll
        for (int c = 0; c < 3; ++c)
            u[c] = bp1[c] + pr0 * Wp1[0 * 3 + c] + pr1 * Wp1[1 * 3 + c] + pr2 * Wp1[2 * 3 + c];
        float m   = (u[0] + u[1] + u[2]) * (1.f / 3.f);
        float d0 = u[0] - m, d1 = u[1] - m, d2 = u[2] - m;
        float var = (d0 * d0 + d1 * d1 + d2 * d2) * (1.f / 3.f);
        float inv = rsqrtf(var + EPSF);
        #pragma unroll
        for (int c = 0; c < 3; ++c)
            s_t[ss][c] = fmaxf((u[c] - m) * inv * gp[c] + betap[c], 0.f);
    }
    __syncthreads();

    const int j = idx[n * NS + s];
    const float t0 = s_t[s][0], t1 = s_t[s][1], t2 = s_t[s][2];
    const int obase = h * DH;

    // pe (packed): pe2[i] = bp2p + t0*W0p + t1*W1p + t2*W2p
    __attribute__((aligned(16))) h2 pe2[8];
    {
        h2 t02 = asH2(pk2(t0, t0));
        h2 t12 = asH2(pk2(t1, t1));
        h2 t22 = asH2(pk2(t2, t2));
        const uint* W0p = PK + PK_WP2 + 0 * 64 + h * 8;
        const uint* W1p = PK + PK_WP2 + 1 * 64 + h * 8;
        const uint* W2p = PK + PK_WP2 + 2 * 64 + h * 8;
        const uint* Bp  = PK + PK_BP2 + h * 8;
        #pragma unroll
        for (int i = 0; i < 8; ++i) {
            h2 acc = asH2(Bp[i]);
            acc = acc + t02 * asH2(W0p[i]);
            acc = acc + t12 * asH2(W1p[i]);
            acc = acc + t22 * asH2(W2p[i]);
            pe2[i] = acc;
        }
    }

    // gather q,k,v (f16, stays packed) and build r = k + pe - q
    __attribute__((aligned(16))) h2 v2[8], r2[8];
    {
        __attribute__((aligned(16))) h2 k2[8], q2[8];
        const uint4* k4 = (const uint4*)(xk + (size_t)j * OC + obase);
        const uint4* v4 = (const uint4*)(xv + (size_t)j * OC + obase);
        const uint4* q4 = (const uint4*)(xq + (size_t)n * OC + obase);
        *(uint4*)&k2[0] = k4[0]; *(uint4*)&k2[4] = k4[1];
        *(uint4*)&v2[0] = v4[0]; *(uint4*)&v2[4] = v4[1];
        *(uint4*)&q2[0] = q4[0]; *(uint4*)&q2[4] = q4[1];
        #pragma unroll
        for (int i = 0; i < 8; ++i)
            r2[i] = (k2[i] + pe2[i]) - q2[i];
    }

    // LN1 (packed stats) + relu -> a2
    __attribute__((aligned(16))) h2 a2[8];
    {
        h2 sum2 = r2[0];
        #pragma unroll
        for (int i = 1; i < 8; ++i) sum2 = sum2 + r2[i];
        float m = ((float)sum2[0] + (float)sum2[1]) * (1.f / DH);
        h2 m2 = asH2(pk2(m, m));
        h2 vs2 = {(__fp16)0.f, (__fp16)0.f};
        #pragma unroll
        for (int i = 0; i < 8; ++i) {
            r2[i] = r2[i] - m2;            // d2
            vs2 = vs2 + r2[i] * r2[i];
        }
        float var = ((float)vs2[0] + (float)vs2[1]) * (1.f / DH);
        float inv = rsqrtf(var + EPSF);
        h2 inv2 = asH2(pk2(inv, inv));
        h2 z2 = {(__fp16)0.f, (__fp16)0.f};
        #pragma unroll
        for (int i = 0; i < 8; ++i) {
            h2 gi = asH2(PK[PK_GW1 + i]) * inv2;
            a2[i] = PKMAX(r2[i] * gi + asH2(PK[PK_BW1P + i]), z2);
        }
    }

    // w1 = a @ Ww1 + bw1 (fdot2, packed a direct)
    float w1[OSH];
    #pragma unroll
    for (int o2 = 0; o2 < OSH; ++o2) w1[o2] = FPK[PKF_BW1 + o2];
    #pragma unroll
    for (int dp = 0; dp < 8; ++dp) {
        #pragma unroll
        for (int o2 = 0; o2 < OSH; ++o2)
            w1[o2] = __builtin_amdgcn_fdot2(a2[dp], asH2(PK[PK_WW1 + dp * 16 + o2]), w1[o2], false);
    }

    // LN2 (packed) + relu, fused (@Ww2 + bw2).mean via rmean pairs
    float logit;
    {
        __attribute__((aligned(16))) h2 w2[8];
        #pragma unroll
        for (int i = 0; i < 8; ++i) w2[i] = asH2(pk2(w1[2 * i], w1[2 * i + 1]));
        h2 sum2 = w2[0];
        #pragma unroll
        for (int i = 1; i < 8; ++i) sum2 = sum2 + w2[i];
        float m = ((float)sum2[0] + (float)sum2[1]) * (1.f / OSH);
        h2 m2 = asH2(pk2(m, m));
        h2 vs2 = {(__fp16)0.f, (__fp16)0.f};
        #pragma unroll
        for (int i = 0; i < 8; ++i) {
            w2[i] = w2[i] - m2;
            vs2 = vs2 + w2[i] * w2[i];
        }
        float var = ((float)vs2[0] + (float)vs2[1]) * (1.f / OSH);
        float inv = rsqrtf(var + EPSF);
        h2 inv2 = asH2(pk2(inv, inv));
        h2 z2 = {(__fp16)0.f, (__fp16)0.f};
        logit = FPK[PKF_RMB];
        #pragma unroll
        for (int i = 0; i < 8; ++i) {
            h2 gi = asH2(PK[PK_GW2 + i]) * inv2;
            h2 bv2 = PKMAX(w2[i] * gi + asH2(PK[PK_BW2P + i]), z2);
            logit = __builtin_amdgcn_fdot2(bv2, asH2(PK[PK_RM + i]), logit, false);
        }
    }

    s_logit[s][h] = logit;
    __syncthreads();

    if (t < NH) {
        float mx = -1e30f;
        #pragma unroll
        for (int ss = 0; ss < NS; ++ss) mx = fmaxf(mx, s_logit[ss][t]);
        float denom = 0.f;
        #pragma unroll
        for (int ss = 0; ss < NS; ++ss) denom += __expf(s_logit[ss][t] - mx);
        s_mx[t] = mx;
        s_inv[t] = 1.f / denom;
    }
    __syncthreads();

    float w = __expf(logit - s_mx[h]) * s_inv[h];

    // contrib (packed): c2 = (v2 + pe2) * w
    {
        h2 w2p = asH2(pk2(w, w));
        __attribute__((aligned(16))) h2 c2[8];
        #pragma unroll
        for (int i = 0; i < 8; ++i)
            c2[i] = (v2[i] + pe2[i]) * w2p;
        *(uint4*)&s_c[s][h * 8]     = *(uint4*)&c2[0];
        *(uint4*)&s_c[s][h * 8 + 4] = *(uint4*)&c2[4];
    }
    __syncthreads();

    // reduce over s: output element t = (head t>>4, d t&15); packed column sum
    {
        const int oh = t >> 4;
        const int od = t & 15;
        const int col = oh * 8 + (od >> 1);
        h2 acc2 = {(__fp16)0.f, (__fp16)0.f};
        #pragma unroll
        for (int ss = 0; ss < NS; ++ss)
            acc2 = acc2 + asH2(s_c[ss][col]);
        out[(size_t)n * OC + t] = (float)acc2[od & 1];
    }
}

// ---------------------------------------------------------------------------
extern "C" void kernel_launch(void* const* d_in, const int* in_sizes, int n_in,
                              void* d_out, int out_size, void* d_ws, size_t ws_size,
                              hipStream_t stream) {
    const float* p     = (const float*)d_in[0];
    const float* x     = (const float*)d_in[1];
    const int*   idx   = (const int*)d_in[2];
    const float* Wq    = (const float*)d_in[3];
    const float* bq    = (const float*)d_in[4];
    const float* Wk    = (const float*)d_in[5];
    const float* bk    = (const float*)d_in[6];
    const float* Wv    = (const float*)d_in[7];
    const float* bv    = (const float*)d_in[8];
    const float* Wp1   = (const float*)d_in[9];
    const float* bp1   = (const float*)d_in[10];
    const float* gp    = (const float*)d_in[11];
    const float* betap = (const float*)d_in[12];
    const float* Wp2   = (const float*)d_in[13];
    const float* bp2   = (const float*)d_in[14];
    const float* gw1   = (const float*)d_in[15];
    const float* betaw1= (const float*)d_in[16];
    const float* Ww1   = (const float*)d_in[17];
    const float* bw1   = (const float*)d_in[18];
    const float* gw2   = (const float*)d_in[19];
    const float* betaw2= (const float*)d_in[20];
    const float* Ww2   = (const float*)d_in[21];
    const float* bw2   = (const float*)d_in[22];
    float* out = (float*)d_out;

    ushort* xb = (ushort*)d_ws;                        // NPAD*128 bf16
    ushort* WT = xb + (size_t)NPAD * CIN;              // 3*128*128 bf16
    ushort* xq = WT + 3 * OC * CIN;                    // N*128 f16
    ushort* xk = xq + (size_t)NPTS * OC;
    ushort* xv = xk + (size_t)NPTS * OC;
    uint*   PACKS = (uint*)(xv + (size_t)NPTS * OC);   // 448 uints

    prep_kernel<<<XB_BLOCKS + 4, 256, 0, stream>>>(x, Wq, Wk, Wv,
                                                   Wp2, bp2, gw1, betaw1,
                                                   Ww1, bw1, gw2, betaw2, Ww2, bw2,
                                                   xb, WT, PACKS);

    dim3 g1(NPAD / 128, 3);   // 235 x 3
    qkv_mfma<<<g1, 256, 0, stream>>>(xb, WT, bq, bk, bv, xq, xk, xv);

    attn_kernel<<<NPTS, 128, 0, stream>>>(p, idx, xq, xk, xv,
                                          Wp1, bp1, gp, betap,
                                          PACKS, out);
}

// Round 11
// 196.016 us; speedup vs baseline: 1.1460x; 1.0010x over previous
//
#include <hip/hip_runtime.h>
#include <math.h>

typedef unsigned int  uint;
typedef unsigned short ushort;

// Problem constants
constexpr int NPTS = 30000;
constexpr int NPAD = 30080;  // 235 * 128
constexpr int CIN  = 128;
constexpr int OC   = 128;   // O
constexpr int NH   = 8;     // heads
constexpr int NS   = 16;    // neighbors
constexpr int DH   = 16;    // O/H
constexpr int OSH  = 16;    // O/SHARE
constexpr float EPSF = 1e-5f;

typedef __attribute__((ext_vector_type(8))) short  bf16x8;
typedef __attribute__((ext_vector_type(4))) float  f32x4;
typedef __attribute__((ext_vector_type(2))) __fp16 h2;

__device__ __forceinline__ ushort f2bf(float f) {
    uint u = __float_as_uint(f);
    u += 0x7fff + ((u >> 16) & 1);   // RNE
    return (ushort)(u >> 16);
}
__device__ __forceinline__ ushort f2h(float f) {
    __fp16 h = (__fp16)f;
    return *(ushort*)&h;
}
__device__ __forceinline__ uint pk2(float a, float b) {
    h2 v = __builtin_amdgcn_cvt_pkrtz(a, b);
    return *(uint*)&v;
}
__device__ __forceinline__ h2 asH2(uint u) { return *(h2*)&u; }

#if defined(__has_builtin)
#if __has_builtin(__builtin_elementwise_max)
#define PKMAX(a, b) __builtin_elementwise_max(a, b)
#endif
#endif
#ifndef PKMAX
__device__ __forceinline__ h2 PKMAX(h2 a, h2 b) {
    h2 r; r[0] = a[0] > b[0] ? a[0] : b[0]; r[1] = a[1] > b[1] ? a[1] : b[1]; return r;
}
#endif

// PACKS layout (uints):
constexpr int PK_WW1   = 0;     // 128: pairs (Ww1[2dp][o], Ww1[2dp+1][o]) at [dp*16+o]
constexpr int PK_WP2   = 128;   // 192: c=0..2 pairs over o
constexpr int PK_BP2   = 320;   // 64
constexpr int PK_GW1   = 384;
constexpr int PK_BW1P  = 392;   // betaw1 pairs
constexpr int PK_GW2   = 400;
constexpr int PK_BW2P  = 408;   // betaw2 pairs
constexpr int PK_RM    = 416;   // rowmean(Ww2) pairs
constexpr int PKF_BW1  = 424;   // float view: bw1[16]
constexpr int PKF_RMB  = 440;   // float view: mean(bw2)

// ---------------------------------------------------------------------------
// Kernel 0: prep (unchanged from r10).
// ---------------------------------------------------------------------------
constexpr int XB_BLOCKS = (NPAD * CIN / 4) / 256;   // 3760

__global__ __launch_bounds__(256) void prep_kernel(
    const float* __restrict__ x,
    const float* __restrict__ Wq, const float* __restrict__ Wk, const float* __restrict__ Wv,
    const float* __restrict__ Wp2, const float* __restrict__ bp2,
    const float* __restrict__ gw1, const float* __restrict__ betaw1,
    const float* __restrict__ Ww1, const float* __restrict__ bw1,
    const float* __restrict__ gw2, const float* __restrict__ betaw2,
    const float* __restrict__ Ww2, const float* __restrict__ bw2,
    ushort* __restrict__ xb, ushort* __restrict__ WT, uint* __restrict__ PK)
{
    const int b = blockIdx.x;
    const int t = threadIdx.x;
    if (b < XB_BLOCKS) {
        int e   = (b * 256 + t) * 4;
        int row = e >> 7;
        uint2 o = make_uint2(0, 0);
        if (row < NPTS) {
            float4 f = *(const float4*)(x + e);
            o.x = (uint)f2bf(f.x) | ((uint)f2bf(f.y) << 16);
            o.y = (uint)f2bf(f.z) | ((uint)f2bf(f.w) << 16);
        }
        *(uint2*)(xb + e) = o;
    } else if (b < XB_BLOCKS + 3) {
        int mat = b - XB_BLOCKS;
        const float* W = (mat == 0) ? Wq : (mat == 1 ? Wk : Wv);
        ushort* T = WT + mat * OC * CIN;
        if (t < OC) {
            for (int k = 0; k < CIN; ++k)
                T[t * CIN + k] = f2bf(W[k * OC + t]);
        }
    } else {
        float* FPK = (float*)PK;
        if (t < 128) {
            int dp = t >> 4, o = t & 15;
            PK[PK_WW1 + t] = pk2(Ww1[(2 * dp) * OSH + o], Ww1[(2 * dp + 1) * OSH + o]);
        }
        if (t < 192) {
            int c = t >> 6, jj = t & 63;
            PK[PK_WP2 + t] = pk2(Wp2[c * OC + 2 * jj], Wp2[c * OC + 2 * jj + 1]);
        }
        if (t < 64)
            PK[PK_BP2 + t] = pk2(bp2[2 * t], bp2[2 * t + 1]);
        if (t < 8) {
            PK[PK_GW1 + t]  = pk2(gw1[2 * t],    gw1[2 * t + 1]);
            PK[PK_BW1P + t] = pk2(betaw1[2 * t], betaw1[2 * t + 1]);
            PK[PK_GW2 + t]  = pk2(gw2[2 * t],    gw2[2 * t + 1]);
            PK[PK_BW2P + t] = pk2(betaw2[2 * t], betaw2[2 * t + 1]);
            float r0 = 0.f, r1 = 0.f;
            #pragma unroll
            for (int o2 = 0; o2 < OSH; ++o2) {
                r0 += Ww2[(2 * t) * OSH + o2];
                r1 += Ww2[(2 * t + 1) * OSH + o2];
            }
            PK[PK_RM + t] = pk2(r0 * (1.f / OSH), r1 * (1.f / OSH));
        }
        if (t < 16)
            FPK[PKF_BW1 + t] = bw1[t];
        if (t == 16) {
            float acc = 0.f;
            #pragma unroll
            for (int o2 = 0; o2 < OSH; ++o2) acc += bw2[o2];
            FPK[PKF_RMB] = acc * (1.f / OSH);
        }
    }
}

// ---------------------------------------------------------------------------
// Kernel 1: QKV projection via bf16 MFMA (unchanged from r10). Outputs f16.
// ---------------------------------------------------------------------------
__global__ __launch_bounds__(256) void qkv_mfma(
    const ushort* __restrict__ xb, const ushort* __restrict__ WT,
    const float* __restrict__ bq, const float* __restrict__ bk, const float* __restrict__ bv,
    ushort* __restrict__ yq, ushort* __restrict__ yk, ushort* __restrict__ yv)
{
    const int mat = blockIdx.y;
    const float* bias = (mat == 0) ? bq : (mat == 1 ? bk : bv);
    ushort* y         = (mat == 0) ? yq : (mat == 1 ? yk : yv);
    const ushort* T   = WT + mat * OC * CIN;

    const int n0   = blockIdx.x * 128;
    const int t    = threadIdx.x;
    const int wave = t >> 6;
    const int lane = t & 63;
    const int m16  = lane & 15;
    const int quad = lane >> 4;

    f32x4 acc[2][8];
    #pragma unroll
    for (int mt = 0; mt < 2; ++mt)
        #pragma unroll
        for (int nt = 0; nt < 8; ++nt)
            acc[mt][nt] = (f32x4){0.f, 0.f, 0.f, 0.f};

    const ushort* arow0 = xb + (size_t)(n0 + wave * 32 + m16) * CIN;
    const ushort* arow1 = arow0 + 16 * CIN;

    #pragma unroll
    for (int ks = 0; ks < 4; ++ks) {
        const int kb = ks * 32 + quad * 8;
        bf16x8 a0 = *(const bf16x8*)(arow0 + kb);
        bf16x8 a1 = *(const bf16x8*)(arow1 + kb);
        #pragma unroll
        for (int nt = 0; nt < 8; ++nt) {
            bf16x8 bfr = *(const bf16x8*)(T + (size_t)(nt * 16 + m16) * CIN + kb);
            acc[0][nt] = __builtin_amdgcn_mfma_f32_16x16x32_bf16(a0, bfr, acc[0][nt], 0, 0, 0);
            acc[1][nt] = __builtin_amdgcn_mfma_f32_16x16x32_bf16(a1, bfr, acc[1][nt], 0, 0, 0);
        }
    }

    #pragma unroll
    for (int mt = 0; mt < 2; ++mt) {
        #pragma unroll
        for (int nt = 0; nt < 8; ++nt) {
            const int col = nt * 16 + m16;
            const float bcol = bias[col];
            #pragma unroll
            for (int r = 0; r < 4; ++r) {
                int row = n0 + wave * 32 + mt * 16 + quad * 4 + r;
                if (row < NPTS)
                    y[(size_t)row * OC + col] = f2h(acc[mt][nt][r] + bcol);
            }
        }
    }
}

// ---------------------------------------------------------------------------
// Kernel 2: per-point attention. 1 point/block, 128 threads.
// Remapped: s = t&15, h = t>>4 -> all 16 neighbors of a head in one 16-lane
// group; softmax via __shfl_xor butterfly (no LDS, no barriers). pr-MLP
// inlined per-thread (redundant x8, L1-hot). ONE barrier total (contrib).
// ---------------------------------------------------------------------------
__global__ __launch_bounds__(128) void attn_kernel(
    const float* __restrict__ p, const int* __restrict__ idx,
    const ushort* __restrict__ xq, const ushort* __restrict__ xk, const ushort* __restrict__ xv,
    const float* __restrict__ Wp1, const float* __restrict__ bp1,
    const float* __restrict__ gp,  const float* __restrict__ betap,
    const uint* __restrict__ PK,
    float* __restrict__ out)
{
    const int n = blockIdx.x;
    const int t = threadIdx.x;   // 0..127
    const int s = t & 15;        // neighbor
    const int h = t >> 4;        // head 0..7

    const float* FPK = (const float*)PK;

    __shared__ uint s_c[NS][68];   // packed f16 contrib pairs, 4352 B

    const int j = idx[n * NS + s];

    // inline pr-MLP (3-wide): u = pr @ Wp1 + bp1; LN3; relu
    float t0, t1, t2;
    {
        float pr0 = p[j * 3 + 0] - p[n * 3 + 0];
        float pr1 = p[j * 3 + 1] - p[n * 3 + 1];
        float pr2 = p[j * 3 + 2] - p[n * 3 + 2];
        float u[3];
        #pragma unroll
        for (int c = 0; c < 3; ++c)
            u[c] = bp1[c] + pr0 * Wp1[0 * 3 + c] + pr1 * Wp1[1 * 3 + c] + pr2 * Wp1[2 * 3 + c];
        float m   = (u[0] + u[1] + u[2]) * (1.f / 3.f);
        float d0 = u[0] - m, d1 = u[1] - m, d2 = u[2] - m;
        float var = (d0 * d0 + d1 * d1 + d2 * d2) * (1.f / 3.f);
        float inv = rsqrtf(var + EPSF);
        t0 = fmaxf((u[0] - m) * inv * gp[0] + betap[0], 0.f);
        t1 = fmaxf((u[1] - m) * inv * gp[1] + betap[1], 0.f);
        t2 = fmaxf((u[2] - m) * inv * gp[2] + betap[2], 0.f);
    }

    const int obase = h * DH;

    // pe (packed)
    __attribute__((aligned(16))) h2 pe2[8];
    {
        h2 t02 = asH2(pk2(t0, t0));
        h2 t12 = asH2(pk2(t1, t1));
        h2 t22 = asH2(pk2(t2, t2));
        const uint* W0p = PK + PK_WP2 + 0 * 64 + h * 8;
        const uint* W1p = PK + PK_WP2 + 1 * 64 + h * 8;
        const uint* W2p = PK + PK_WP2 + 2 * 64 + h * 8;
        const uint* Bp  = PK + PK_BP2 + h * 8;
        #pragma unroll
        for (int i = 0; i < 8; ++i) {
            h2 acc = asH2(Bp[i]);
            acc = acc + t02 * asH2(W0p[i]);
            acc = acc + t12 * asH2(W1p[i]);
            acc = acc + t22 * asH2(W2p[i]);
            pe2[i] = acc;
        }
    }

    // gather q,k,v (f16 packed) and build r = k + pe - q
    __attribute__((aligned(16))) h2 v2[8], r2[8];
    {
        __attribute__((aligned(16))) h2 k2[8], q2[8];
        const uint4* k4 = (const uint4*)(xk + (size_t)j * OC + obase);
        const uint4* v4 = (const uint4*)(xv + (size_t)j * OC + obase);
        const uint4* q4 = (const uint4*)(xq + (size_t)n * OC + obase);
        *(uint4*)&k2[0] = k4[0]; *(uint4*)&k2[4] = k4[1];
        *(uint4*)&v2[0] = v4[0]; *(uint4*)&v2[4] = v4[1];
        *(uint4*)&q2[0] = q4[0]; *(uint4*)&q2[4] = q4[1];
        #pragma unroll
        for (int i = 0; i < 8; ++i)
            r2[i] = (k2[i] + pe2[i]) - q2[i];
    }

    // LN1 (packed) + relu -> a2
    __attribute__((aligned(16))) h2 a2[8];
    {
        h2 sum2 = r2[0];
        #pragma unroll
        for (int i = 1; i < 8; ++i) sum2 = sum2 + r2[i];
        float m = ((float)sum2[0] + (float)sum2[1]) * (1.f / DH);
        h2 m2 = asH2(pk2(m, m));
        h2 vs2 = {(__fp16)0.f, (__fp16)0.f};
        #pragma unroll
        for (int i = 0; i < 8; ++i) {
            r2[i] = r2[i] - m2;
            vs2 = vs2 + r2[i] * r2[i];
        }
        float var = ((float)vs2[0] + (float)vs2[1]) * (1.f / DH);
        float inv = rsqrtf(var + EPSF);
        h2 inv2 = asH2(pk2(inv, inv));
        h2 z2 = {(__fp16)0.f, (__fp16)0.f};
        #pragma unroll
        for (int i = 0; i < 8; ++i) {
            h2 gi = asH2(PK[PK_GW1 + i]) * inv2;
            a2[i] = PKMAX(r2[i] * gi + asH2(PK[PK_BW1P + i]), z2);
        }
    }

    // w1 = a @ Ww1 + bw1 (fdot2)
    float w1[OSH];
    #pragma unroll
    for (int o2 = 0; o2 < OSH; ++o2) w1[o2] = FPK[PKF_BW1 + o2];
    #pragma unroll
    for (int dp = 0; dp < 8; ++dp) {
        #pragma unroll
        for (int o2 = 0; o2 < OSH; ++o2)
            w1[o2] = __builtin_amdgcn_fdot2(a2[dp], asH2(PK[PK_WW1 + dp * 16 + o2]), w1[o2], false);
    }

    // LN2 (packed) + relu, fused (@Ww2 + bw2).mean via rmean pairs
    float logit;
    {
        __attribute__((aligned(16))) h2 w2[8];
        #pragma unroll
        for (int i = 0; i < 8; ++i) w2[i] = asH2(pk2(w1[2 * i], w1[2 * i + 1]));
        h2 sum2 = w2[0];
        #pragma unroll
        for (int i = 1; i < 8; ++i) sum2 = sum2 + w2[i];
        float m = ((float)sum2[0] + (float)sum2[1]) * (1.f / OSH);
        h2 m2 = asH2(pk2(m, m));
        h2 vs2 = {(__fp16)0.f, (__fp16)0.f};
        #pragma unroll
        for (int i = 0; i < 8; ++i) {
            w2[i] = w2[i] - m2;
            vs2 = vs2 + w2[i] * w2[i];
        }
        float var = ((float)vs2[0] + (float)vs2[1]) * (1.f / OSH);
        float inv = rsqrtf(var + EPSF);
        h2 inv2 = asH2(pk2(inv, inv));
        h2 z2 = {(__fp16)0.f, (__fp16)0.f};
        logit = FPK[PKF_RMB];
        #pragma unroll
        for (int i = 0; i < 8; ++i) {
            h2 gi = asH2(PK[PK_GW2 + i]) * inv2;
            h2 bv2 = PKMAX(w2[i] * gi + asH2(PK[PK_BW2P + i]), z2);
            logit = __builtin_amdgcn_fdot2(bv2, asH2(PK[PK_RM + i]), logit, false);
        }
    }

    // softmax over s: 16-lane butterfly (s = lane&15 within each wave)
    float w;
    {
        float mx = logit;
        #pragma unroll
        for (int mask = 1; mask < 16; mask <<= 1)
            mx = fmaxf(mx, __shfl_xor(mx, mask));
        float e = __expf(logit - mx);
        float den = e;
        #pragma unroll
        for (int mask = 1; mask < 16; mask <<= 1)
            den += __shfl_xor(den, mask);
        w = e / den;
    }

    // contrib (packed): c2 = (v2 + pe2) * w
    {
        h2 w2p = asH2(pk2(w, w));
        __attribute__((aligned(16))) h2 c2[8];
        #pragma unroll
        for (int i = 0; i < 8; ++i)
            c2[i] = (v2[i] + pe2[i]) * w2p;
        *(uint4*)&s_c[s][h * 8]     = *(uint4*)&c2[0];
        *(uint4*)&s_c[s][h * 8 + 4] = *(uint4*)&c2[4];
    }
    __syncthreads();

    // reduce over s: output element t = (head t>>4, d t&15); packed column sum
    {
        const int oh = t >> 4;
        const int od = t & 15;
        const int col = oh * 8 + (od >> 1);
        h2 acc2 = {(__fp16)0.f, (__fp16)0.f};
        #pragma unroll
        for (int ss = 0; ss < NS; ++ss)
            acc2 = acc2 + asH2(s_c[ss][col]);
        out[(size_t)n * OC + t] = (float)acc2[od & 1];
    }
}

// ---------------------------------------------------------------------------
extern "C" void kernel_launch(void* const* d_in, const int* in_sizes, int n_in,
                              void* d_out, int out_size, void* d_ws, size_t ws_size,
                              hipStream_t stream) {
    const float* p     = (const float*)d_in[0];
    const float* x     = (const float*)d_in[1];
    const int*   idx   = (const int*)d_in[2];
    const float* Wq    = (const float*)d_in[3];
    const float* bq    = (const float*)d_in[4];
    const float* Wk    = (const float*)d_in[5];
    const float* bk    = (const float*)d_in[6];
    const float* Wv    = (const float*)d_in[7];
    const float* bv    = (const float*)d_in[8];
    const float* Wp1   = (const float*)d_in[9];
    const float* bp1   = (const float*)d_in[10];
    const float* gp    = (const float*)d_in[11];
    const float* betap = (const float*)d_in[12];
    const float* Wp2   = (const float*)d_in[13];
    const float* bp2   = (const float*)d_in[14];
    const float* gw1   = (const float*)d_in[15];
    const float* betaw1= (const float*)d_in[16];
    const float* Ww1   = (const float*)d_in[17];
    const float* bw1   = (const float*)d_in[18];
    const float* gw2   = (const float*)d_in[19];
    const float* betaw2= (const float*)d_in[20];
    const float* Ww2   = (const float*)d_in[21];
    const float* bw2   = (const float*)d_in[22];
    float* out = (float*)d_out;

    ushort* xb = (ushort*)d_ws;                        // NPAD*128 bf16
    ushort* WT = xb + (size_t)NPAD * CIN;              // 3*128*128 bf16
    ushort* xq = WT + 3 * OC * CIN;                    // N*128 f16
    ushort* xk = xq + (size_t)NPTS * OC;
    ushort* xv = xk + (size_t)NPTS * OC;
    uint*   PACKS = (uint*)(xv + (size_t)NPTS * OC);   // 448 uints

    prep_kernel<<<XB_BLOCKS + 4, 256, 0, stream>>>(x, Wq, Wk, Wv,
                                                   Wp2, bp2, gw1, betaw1,
                                                   Ww1, bw1, gw2, betaw2, Ww2, bw2,
                                                   xb, WT, PACKS);

    dim3 g1(NPAD / 128, 3);   // 235 x 3
    qkv_mfma<<<g1, 256, 0, stream>>>(xb, WT, bq, bk, bv, xq, xk, xv);

    attn_kernel<<<NPTS, 128, 0, stream>>>(p, idx, xq, xk, xv,
                                          Wp1, bp1, gp, betap,
                                          PACKS, out);
}

// Round 12
// 186.644 us; speedup vs baseline: 1.2035x; 1.0502x over previous
//
#include <hip/hip_runtime.h>
#include <math.h>

typedef unsigned int  uint;
typedef unsigned short ushort;

// Problem constants
constexpr int NPTS = 30000;
constexpr int CIN  = 128;
constexpr int OC   = 128;   // O
constexpr int NH   = 8;     // heads
constexpr int NS   = 16;    // neighbors
constexpr int DH   = 16;    // O/H
constexpr int OSH  = 16;    // O/SHARE
constexpr float EPSF = 1e-5f;

typedef __attribute__((ext_vector_type(8))) __fp16 h8;
typedef __attribute__((ext_vector_type(4))) float  f32x4;
typedef __attribute__((ext_vector_type(2))) __fp16 h2;

__device__ __forceinline__ ushort f2h(float f) {
    __fp16 h = (__fp16)f;
    return *(ushort*)&h;
}
__device__ __forceinline__ uint pk2(float a, float b) {
    h2 v = __builtin_amdgcn_cvt_pkrtz(a, b);
    return *(uint*)&v;
}
__device__ __forceinline__ h2 asH2(uint u) { return *(h2*)&u; }

#if defined(__has_builtin)
#if __has_builtin(__builtin_elementwise_max)
#define PKMAX(a, b) __builtin_elementwise_max(a, b)
#endif
#endif
#ifndef PKMAX
__device__ __forceinline__ h2 PKMAX(h2 a, h2 b) {
    h2 r; r[0] = a[0] > b[0] ? a[0] : b[0]; r[1] = a[1] > b[1] ? a[1] : b[1]; return r;
}
#endif

// PACKS layout (uints):
constexpr int PK_WW1   = 0;     // 128: pairs (Ww1[2dp][o], Ww1[2dp+1][o]) at [dp*16+o]
constexpr int PK_WP2   = 128;   // 192: c=0..2 pairs over o
constexpr int PK_BP2   = 320;   // 64
constexpr int PK_GW1   = 384;
constexpr int PK_BW1P  = 392;   // betaw1 pairs
constexpr int PK_GW2   = 400;
constexpr int PK_BW2P  = 408;   // betaw2 pairs
constexpr int PK_RM    = 416;   // rowmean(Ww2) pairs
constexpr int PKF_BW1  = 424;   // float view: bw1[16]
constexpr int PKF_RMB  = 440;   // float view: mean(bw2)

// ---------------------------------------------------------------------------
// Kernel 0: prep (tiny now — no x pass).
// Blocks [0,24): W{q,k,v} -> f16 transposed WT[o][k]; 8 blocks per mat.
// Block 24: PACKS.
// ---------------------------------------------------------------------------
__global__ __launch_bounds__(256) void prep_kernel(
    const float* __restrict__ Wq, const float* __restrict__ Wk, const float* __restrict__ Wv,
    const float* __restrict__ Wp2, const float* __restrict__ bp2,
    const float* __restrict__ gw1, const float* __restrict__ betaw1,
    const float* __restrict__ Ww1, const float* __restrict__ bw1,
    const float* __restrict__ gw2, const float* __restrict__ betaw2,
    const float* __restrict__ Ww2, const float* __restrict__ bw2,
    ushort* __restrict__ WT, uint* __restrict__ PK)
{
    const int b = blockIdx.x;
    const int t = threadIdx.x;
    if (b < 24) {
        const int mat = b >> 3;           // 0..2
        const int cg  = b & 7;            // col group of 16
        const float* W = (mat == 0) ? Wq : (mat == 1 ? Wk : Wv);
        const int col = cg * 16 + (t >> 4);
        const int k0  = (t & 15) * 8;
        float v0 = W[(k0 + 0) * OC + col], v1 = W[(k0 + 1) * OC + col];
        float v2 = W[(k0 + 2) * OC + col], v3 = W[(k0 + 3) * OC + col];
        float v4 = W[(k0 + 4) * OC + col], v5 = W[(k0 + 5) * OC + col];
        float v6 = W[(k0 + 6) * OC + col], v7 = W[(k0 + 7) * OC + col];
        uint4 u = make_uint4(pk2(v0, v1), pk2(v2, v3), pk2(v4, v5), pk2(v6, v7));
        *(uint4*)&WT[(size_t)mat * OC * CIN + (size_t)col * CIN + k0] = u;
    } else {
        float* FPK = (float*)PK;
        if (t < 128) {
            int dp = t >> 4, o = t & 15;
            PK[PK_WW1 + t] = pk2(Ww1[(2 * dp) * OSH + o], Ww1[(2 * dp + 1) * OSH + o]);
        }
        if (t < 192) {
            int c = t >> 6, jj = t & 63;
            PK[PK_WP2 + t] = pk2(Wp2[c * OC + 2 * jj], Wp2[c * OC + 2 * jj + 1]);
        }
        if (t < 64)
            PK[PK_BP2 + t] = pk2(bp2[2 * t], bp2[2 * t + 1]);
        if (t < 8) {
            PK[PK_GW1 + t]  = pk2(gw1[2 * t],    gw1[2 * t + 1]);
            PK[PK_BW1P + t] = pk2(betaw1[2 * t], betaw1[2 * t + 1]);
            PK[PK_GW2 + t]  = pk2(gw2[2 * t],    gw2[2 * t + 1]);
            PK[PK_BW2P + t] = pk2(betaw2[2 * t], betaw2[2 * t + 1]);
            float r0 = 0.f, r1 = 0.f;
            #pragma unroll
            for (int o2 = 0; o2 < OSH; ++o2) {
                r0 += Ww2[(2 * t) * OSH + o2];
                r1 += Ww2[(2 * t + 1) * OSH + o2];
            }
            PK[PK_RM + t] = pk2(r0 * (1.f / OSH), r1 * (1.f / OSH));
        }
        if (t < 16)
            FPK[PKF_BW1 + t] = bw1[t];
        if (t == 16) {
            float acc = 0.f;
            #pragma unroll
            for (int o2 = 0; o2 < OSH; ++o2) acc += bw2[o2];
            FPK[PKF_RMB] = acc * (1.f / OSH);
        }
    }
}

// ---------------------------------------------------------------------------
// Kernel 1: QKV projection via f16 MFMA (16x16x32), staging-free.
// A-fragments loaded directly from fp32 x (2x float4 + 4x cvt_pkrtz each);
// B-fragments from pre-transposed f16 WT. Outputs f16.
// Tail: A-row indices clamped to NPTS-1 (garbage only reaches masked rows).
// ---------------------------------------------------------------------------
__global__ __launch_bounds__(256) void qkv_mfma(
    const float* __restrict__ x, const ushort* __restrict__ WT,
    const float* __restrict__ bq, const float* __restrict__ bk, const float* __restrict__ bv,
    ushort* __restrict__ yq, ushort* __restrict__ yk, ushort* __restrict__ yv)
{
    const int mat = blockIdx.y;
    const float* bias = (mat == 0) ? bq : (mat == 1 ? bk : bv);
    ushort* y         = (mat == 0) ? yq : (mat == 1 ? yk : yv);
    const ushort* T   = WT + (size_t)mat * OC * CIN;

    const int n0   = blockIdx.x * 128;
    const int t    = threadIdx.x;
    const int wave = t >> 6;
    const int lane = t & 63;
    const int m16  = lane & 15;
    const int quad = lane >> 4;

    f32x4 acc[2][8];
    #pragma unroll
    for (int mt = 0; mt < 2; ++mt)
        #pragma unroll
        for (int nt = 0; nt < 8; ++nt)
            acc[mt][nt] = (f32x4){0.f, 0.f, 0.f, 0.f};

    int r0i = n0 + wave * 32 + m16;      // A row for mt=0
    int r1i = r0i + 16;                  // A row for mt=1
    if (r0i > NPTS - 1) r0i = NPTS - 1;
    if (r1i > NPTS - 1) r1i = NPTS - 1;
    const float* arow0 = x + (size_t)r0i * CIN;
    const float* arow1 = x + (size_t)r1i * CIN;

    #pragma unroll
    for (int ks = 0; ks < 4; ++ks) {
        const int kb = ks * 32 + quad * 8;
        float4 f00 = *(const float4*)(arow0 + kb);
        float4 f01 = *(const float4*)(arow0 + kb + 4);
        float4 f10 = *(const float4*)(arow1 + kb);
        float4 f11 = *(const float4*)(arow1 + kb + 4);
        uint4 ua0 = make_uint4(pk2(f00.x, f00.y), pk2(f00.z, f00.w),
                               pk2(f01.x, f01.y), pk2(f01.z, f01.w));
        uint4 ua1 = make_uint4(pk2(f10.x, f10.y), pk2(f10.z, f10.w),
                               pk2(f11.x, f11.y), pk2(f11.z, f11.w));
        h8 a0 = *(h8*)&ua0;
        h8 a1 = *(h8*)&ua1;
        #pragma unroll
        for (int nt = 0; nt < 8; ++nt) {
            h8 bfr = *(const h8*)(T + (size_t)(nt * 16 + m16) * CIN + kb);
            acc[0][nt] = __builtin_amdgcn_mfma_f32_16x16x32_f16(a0, bfr, acc[0][nt], 0, 0, 0);
            acc[1][nt] = __builtin_amdgcn_mfma_f32_16x16x32_f16(a1, bfr, acc[1][nt], 0, 0, 0);
        }
    }

    #pragma unroll
    for (int mt = 0; mt < 2; ++mt) {
        #pragma unroll
        for (int nt = 0; nt < 8; ++nt) {
            const int col = nt * 16 + m16;
            const float bcol = bias[col];
            #pragma unroll
            for (int r = 0; r < 4; ++r) {
                int row = n0 + wave * 32 + mt * 16 + quad * 4 + r;
                if (row < NPTS)
                    y[(size_t)row * OC + col] = f2h(acc[mt][nt][r] + bcol);
            }
        }
    }
}

// ---------------------------------------------------------------------------
// Kernel 2: per-point attention (r11 structure; softmax div -> v_rcp).
// ---------------------------------------------------------------------------
__global__ __launch_bounds__(128) void attn_kernel(
    const float* __restrict__ p, const int* __restrict__ idx,
    const ushort* __restrict__ xq, const ushort* __restrict__ xk, const ushort* __restrict__ xv,
    const float* __restrict__ Wp1, const float* __restrict__ bp1,
    const float* __restrict__ gp,  const float* __restrict__ betap,
    const uint* __restrict__ PK,
    float* __restrict__ out)
{
    const int n = blockIdx.x;
    const int t = threadIdx.x;   // 0..127
    const int s = t & 15;        // neighbor
    const int h = t >> 4;        // head 0..7

    const float* FPK = (const float*)PK;

    __shared__ uint s_c[NS][68];   // packed f16 contrib pairs, 4352 B

    const int j = idx[n * NS + s];

    // inline pr-MLP (3-wide): u = pr @ Wp1 + bp1; LN3; relu
    float t0, t1, t2;
    {
        float pr0 = p[j * 3 + 0] - p[n * 3 + 0];
        float pr1 = p[j * 3 + 1] - p[n * 3 + 1];
        float pr2 = p[j * 3 + 2] - p[n * 3 + 2];
        float u[3];
        #pragma unroll
        for (int c = 0; c < 3; ++c)
            u[c] = bp1[c] + pr0 * Wp1[0 * 3 + c] + pr1 * Wp1[1 * 3 + c] + pr2 * Wp1[2 * 3 + c];
        float m   = (u[0] + u[1] + u[2]) * (1.f / 3.f);
        float d0 = u[0] - m, d1 = u[1] - m, d2 = u[2] - m;
        float var = (d0 * d0 + d1 * d1 + d2 * d2) * (1.f / 3.f);
        float inv = rsqrtf(var + EPSF);
        t0 = fmaxf((u[0] - m) * inv * gp[0] + betap[0], 0.f);
        t1 = fmaxf((u[1] - m) * inv * gp[1] + betap[1], 0.f);
        t2 = fmaxf((u[2] - m) * inv * gp[2] + betap[2], 0.f);
    }

    const int obase = h * DH;

    // pe (packed)
    __attribute__((aligned(16))) h2 pe2[8];
    {
        h2 t02 = asH2(pk2(t0, t0));
        h2 t12 = asH2(pk2(t1, t1));
        h2 t22 = asH2(pk2(t2, t2));
        const uint* W0p = PK + PK_WP2 + 0 * 64 + h * 8;
        const uint* W1p = PK + PK_WP2 + 1 * 64 + h * 8;
        const uint* W2p = PK + PK_WP2 + 2 * 64 + h * 8;
        const uint* Bp  = PK + PK_BP2 + h * 8;
        #pragma unroll
        for (int i = 0; i < 8; ++i) {
            h2 acc = asH2(Bp[i]);
            acc = acc + t02 * asH2(W0p[i]);
            acc = acc + t12 * asH2(W1p[i]);
            acc = acc + t22 * asH2(W2p[i]);
            pe2[i] = acc;
        }
    }

    // gather q,k,v (f16 packed) and build r = k + pe - q
    __attribute__((aligned(16))) h2 v2[8], r2[8];
    {
        __attribute__((aligned(16))) h2 k2[8], q2[8];
        const uint4* k4 = (const uint4*)(xk + (size_t)j * OC + obase);
        const uint4* v4 = (const uint4*)(xv + (size_t)j * OC + obase);
        const uint4* q4 = (const uint4*)(xq + (size_t)n * OC + obase);
        *(uint4*)&k2[0] = k4[0]; *(uint4*)&k2[4] = k4[1];
        *(uint4*)&v2[0] = v4[0]; *(uint4*)&v2[4] = v4[1];
        *(uint4*)&q2[0] = q4[0]; *(uint4*)&q2[4] = q4[1];
        #pragma unroll
        for (int i = 0; i < 8; ++i)
            r2[i] = (k2[i] + pe2[i]) - q2[i];
    }

    // LN1 (packed) + relu -> a2
    __attribute__((aligned(16))) h2 a2[8];
    {
        h2 sum2 = r2[0];
        #pragma unroll
        for (int i = 1; i < 8; ++i) sum2 = sum2 + r2[i];
        float m = ((float)sum2[0] + (float)sum2[1]) * (1.f / DH);
        h2 m2 = asH2(pk2(m, m));
        h2 vs2 = {(__fp16)0.f, (__fp16)0.f};
        #pragma unroll
        for (int i = 0; i < 8; ++i) {
            r2[i] = r2[i] - m2;
            vs2 = vs2 + r2[i] * r2[i];
        }
        float var = ((float)vs2[0] + (float)vs2[1]) * (1.f / DH);
        float inv = rsqrtf(var + EPSF);
        h2 inv2 = asH2(pk2(inv, inv));
        h2 z2 = {(__fp16)0.f, (__fp16)0.f};
        #pragma unroll
        for (int i = 0; i < 8; ++i) {
            h2 gi = asH2(PK[PK_GW1 + i]) * inv2;
            a2[i] = PKMAX(r2[i] * gi + asH2(PK[PK_BW1P + i]), z2);
        }
    }

    // w1 = a @ Ww1 + bw1 (fdot2)
    float w1[OSH];
    #pragma unroll
    for (int o2 = 0; o2 < OSH; ++o2) w1[o2] = FPK[PKF_BW1 + o2];
    #pragma unroll
    for (int dp = 0; dp < 8; ++dp) {
        #pragma unroll
        for (int o2 = 0; o2 < OSH; ++o2)
            w1[o2] = __builtin_amdgcn_fdot2(a2[dp], asH2(PK[PK_WW1 + dp * 16 + o2]), w1[o2], false);
    }

    // LN2 (packed) + relu, fused (@Ww2 + bw2).mean via rmean pairs
    float logit;
    {
        __attribute__((aligned(16))) h2 w2[8];
        #pragma unroll
        for (int i = 0; i < 8; ++i) w2[i] = asH2(pk2(w1[2 * i], w1[2 * i + 1]));
        h2 sum2 = w2[0];
        #pragma unroll
        for (int i = 1; i < 8; ++i) sum2 = sum2 + w2[i];
        float m = ((float)sum2[0] + (float)sum2[1]) * (1.f / OSH);
        h2 m2 = asH2(pk2(m, m));
        h2 vs2 = {(__fp16)0.f, (__fp16)0.f};
        #pragma unroll
        for (int i = 0; i < 8; ++i) {
            w2[i] = w2[i] - m2;
            vs2 = vs2 + w2[i] * w2[i];
        }
        float var = ((float)vs2[0] + (float)vs2[1]) * (1.f / OSH);
        float inv = rsqrtf(var + EPSF);
        h2 inv2 = asH2(pk2(inv, inv));
        h2 z2 = {(__fp16)0.f, (__fp16)0.f};
        logit = FPK[PKF_RMB];
        #pragma unroll
        for (int i = 0; i < 8; ++i) {
            h2 gi = asH2(PK[PK_GW2 + i]) * inv2;
            h2 bv2 = PKMAX(w2[i] * gi + asH2(PK[PK_BW2P + i]), z2);
            logit = __builtin_amdgcn_fdot2(bv2, asH2(PK[PK_RM + i]), logit, false);
        }
    }

    // softmax over s: 16-lane butterfly; division via v_rcp (den > 0 always)
    float w;
    {
        float mx = logit;
        #pragma unroll
        for (int mask = 1; mask < 16; mask <<= 1)
            mx = fmaxf(mx, __shfl_xor(mx, mask));
        float e = __expf(logit - mx);
        float den = e;
        #pragma unroll
        for (int mask = 1; mask < 16; mask <<= 1)
            den += __shfl_xor(den, mask);
        w = e * __builtin_amdgcn_rcpf(den);
    }

    // contrib (packed): c2 = (v2 + pe2) * w
    {
        h2 w2p = asH2(pk2(w, w));
        __attribute__((aligned(16))) h2 c2[8];
        #pragma unroll
        for (int i = 0; i < 8; ++i)
            c2[i] = (v2[i] + pe2[i]) * w2p;
        *(uint4*)&s_c[s][h * 8]     = *(uint4*)&c2[0];
        *(uint4*)&s_c[s][h * 8 + 4] = *(uint4*)&c2[4];
    }
    __syncthreads();

    // reduce over s: output element t = (head t>>4, d t&15); packed column sum
    {
        const int oh = t >> 4;
        const int od = t & 15;
        const int col = oh * 8 + (od >> 1);
        h2 acc2 = {(__fp16)0.f, (__fp16)0.f};
        #pragma unroll
        for (int ss = 0; ss < NS; ++ss)
            acc2 = acc2 + asH2(s_c[ss][col]);
        out[(size_t)n * OC + t] = (float)acc2[od & 1];
    }
}

// ---------------------------------------------------------------------------
extern "C" void kernel_launch(void* const* d_in, const int* in_sizes, int n_in,
                              void* d_out, int out_size, void* d_ws, size_t ws_size,
                              hipStream_t stream) {
    const float* p     = (const float*)d_in[0];
    const float* x     = (const float*)d_in[1];
    const int*   idx   = (const int*)d_in[2];
    const float* Wq    = (const float*)d_in[3];
    const float* bq    = (const float*)d_in[4];
    const float* Wk    = (const float*)d_in[5];
    const float* bk    = (const float*)d_in[6];
    const float* Wv    = (const float*)d_in[7];
    const float* bv    = (const float*)d_in[8];
    const float* Wp1   = (const float*)d_in[9];
    const float* bp1   = (const float*)d_in[10];
    const float* gp    = (const float*)d_in[11];
    const float* betap = (const float*)d_in[12];
    const float* Wp2   = (const float*)d_in[13];
    const float* bp2   = (const float*)d_in[14];
    const float* gw1   = (const float*)d_in[15];
    const float* betaw1= (const float*)d_in[16];
    const float* Ww1   = (const float*)d_in[17];
    const float* bw1   = (const float*)d_in[18];
    const float* gw2   = (const float*)d_in[19];
    const float* betaw2= (const float*)d_in[20];
    const float* Ww2   = (const float*)d_in[21];
    const float* bw2   = (const float*)d_in[22];
    float* out = (float*)d_out;

    ushort* WT = (ushort*)d_ws;                        // 3*128*128 f16
    ushort* xq = WT + 3 * OC * CIN;                    // N*128 f16
    ushort* xk = xq + (size_t)NPTS * OC;
    ushort* xv = xk + (size_t)NPTS * OC;
    uint*   PACKS = (uint*)(xv + (size_t)NPTS * OC);   // 448 uints

    prep_kernel<<<25, 256, 0, stream>>>(Wq, Wk, Wv,
                                        Wp2, bp2, gw1, betaw1,
                                        Ww1, bw1, gw2, betaw2, Ww2, bw2,
                                        WT, PACKS);

    dim3 g1((NPTS + 127) / 128, 3);   // 235 x 3
    qkv_mfma<<<g1, 256, 0, stream>>>(x, WT, bq, bk, bv, xq, xk, xv);

    attn_kernel<<<NPTS, 128, 0, stream>>>(p, idx, xq, xk, xv,
                                          Wp1, bp1, gp, betap,
                                          PACKS, out);
}